// Round 3
// baseline (495.188 us; speedup 1.0000x reference)
//
#include <hip/hip_runtime.h>
#include <math.h>

// LESA block for MI355X. N=8, C=512, H=W=28 (HW=784), G=8, QKP=32, VP=64, BP=512.
// All GEMM-shaped math in bf16 MFMA (16x16x32), softmax/bn/epilogues fp32.
// R3: k_attn — logits in registers (L[13][4]), P~ stored bf16 (26KB LDS vs 54KB
// fp32), register softmax (no LDS pass), launch_bounds(256,4) -> 4 blocks/CU.

typedef unsigned short u16;
typedef unsigned int u32;
typedef __bf16 bf16x8 __attribute__((ext_vector_type(8)));
typedef float f32x4 __attribute__((ext_vector_type(4)));

#define INVS 0.99999500003749968f  // 1/sqrt(1+1e-5)
#define MFMA16(a, b, c) __builtin_amdgcn_mfma_f32_16x16x32_bf16(a, b, c, 0, 0, 0)

__device__ inline u16 f2bf(float f) {
  u32 u = __builtin_bit_cast(u32, f);
  return (u16)((u + 0x7fffu + ((u >> 16) & 1u)) >> 16);
}
__device__ inline bf16x8 ld_bf8(const u16* p) {
  int4 v = *reinterpret_cast<const int4*>(p);
  return __builtin_bit_cast(bf16x8, v);
}
__device__ inline bf16x8 pack8(const u16 h[8]) {
  int4 v;
  v.x = (int)((u32)h[0] | ((u32)h[1] << 16));
  v.y = (int)((u32)h[2] | ((u32)h[3] << 16));
  v.z = (int)((u32)h[4] | ((u32)h[5] << 16));
  v.w = (int)((u32)h[6] | ((u32)h[7] << 16));
  return __builtin_bit_cast(bf16x8, v);
}
__device__ inline bf16x8 zero8() {
  int4 z = {0, 0, 0, 0};
  return __builtin_bit_cast(bf16x8, z);
}
__device__ inline float bpermf(float v, int srcl) {
  return __builtin_bit_cast(float,
      __builtin_amdgcn_ds_bpermute(srcl << 2, __builtin_bit_cast(int, v)));
}

// ---------------- prep: weight casts/permutes + relative tables ----------------
__global__ __launch_bounds__(256) void k_prep(
    const float* __restrict__ qkv_w, const float* __restrict__ xw2,
    const float* __restrict__ rw, const float* __restrict__ pw,
    const float* __restrict__ xw1, const float* __restrict__ rel,
    u16* __restrict__ Wq, u16* __restrict__ W2, u16* __restrict__ Wr,
    u16* __restrict__ Wp, u16* __restrict__ W1t, u16* __restrict__ relq,
    u16* __restrict__ relk, u16* __restrict__ relv) {
  int idx = blockIdx.x * 256 + threadIdx.x;
  if (idx < 524288) { Wq[idx] = f2bf(qkv_w[idx]); return; }
  idx -= 524288;
  if (idx < 262144) { W2[idx] = f2bf(xw2[idx]); return; }
  idx -= 262144;
  if (idx < 524288) { Wr[idx] = f2bf(rw[idx]); return; }
  idx -= 524288;
  if (idx < 262144) { Wp[idx] = f2bf(pw[idx]); return; }
  idx -= 262144;
  if (idx < 294912) {  // W1t[(g*9+k9)*64 + oc][ic] = xw1[g*64+oc][ic][kh][kw]
    int gk = idx >> 12, rem = idx & 4095, oc = rem >> 6, ic = rem & 63;
    int g = gk / 9, k9 = gk % 9;
    W1t[idx] = f2bf(xw1[(((g * 64 + oc) * 64) + ic) * 9 + k9]);
    return;
  }
  idx -= 294912;
  if (idx < 51200) {  // relq[t][c] = relative[c][t], t<1600 (pad 0)
    int t = idx >> 5, c = idx & 31;
    relq[idx] = (t < 1567) ? f2bf(rel[c * 1567 + t]) : (u16)0;
    return;
  }
  idx -= 51200;
  if (idx < 51200) {
    int t = idx >> 5, c = idx & 31;
    relk[idx] = (t < 1567) ? f2bf(rel[(32 + c) * 1567 + t]) : (u16)0;
    return;
  }
  idx -= 51200;
  if (idx < 102400) {  // relv[c][t] (c<64, t<1600 pad 0)
    int c = idx / 1600, t = idx % 1600;
    relv[idx] = (t < 1567) ? f2bf(rel[(64 + c) * 1567 + t]) : (u16)0;
    return;
  }
}

// ---------------- transpose x (b,512,784) f32 -> xT (b,784,512) bf16 ----------------
__global__ __launch_bounds__(256) void k_transpose(const float* __restrict__ x,
                                                   u16* __restrict__ xT) {
  const int b = blockIdx.z, c0 = blockIdx.y * 64, n0 = blockIdx.x * 32;
  const int tid = threadIdx.x;
  __shared__ __align__(16) u16 tl[64][36];
#pragma unroll
  for (int h = 0; h < 2; ++h) {
    int cl = (tid >> 3) + h * 32;
    int n4 = (tid & 7) * 4;
    float4 v = {0.f, 0.f, 0.f, 0.f};
    if (n0 + n4 + 3 < 784)
      v = *reinterpret_cast<const float4*>(x + ((size_t)b * 512 + c0 + cl) * 784 + n0 + n4);
    u32 lo = (u32)f2bf(v.x) | ((u32)f2bf(v.y) << 16);
    u32 hi = (u32)f2bf(v.z) | ((u32)f2bf(v.w) << 16);
    *reinterpret_cast<int2*>(&tl[cl][n4]) = make_int2((int)lo, (int)hi);
  }
  __syncthreads();
  int nl = tid >> 3, c8 = (tid & 7) * 8;
  if (n0 + nl < 784) {
    u16 h[8];
#pragma unroll
    for (int e = 0; e < 8; ++e) h[e] = tl[c8 + e][nl];
    *reinterpret_cast<int4*>(xT + ((size_t)b * 784 + n0 + nl) * 512 + c0 + c8) =
        __builtin_bit_cast(int4, pack8(h));
  }
}

// ---------------- qkv GEMM: (1024x512)@(512x784) + bn -> Q,K (j,c) / V (c,j) bf16 ----------------
__global__ __launch_bounds__(256) void k_gemm_qkv(
    const u16* __restrict__ W, const u16* __restrict__ xT,
    const float* __restrict__ gq, const float* __restrict__ bq,
    u16* __restrict__ Qs, u16* __restrict__ Ks, u16* __restrict__ Vs) {
  const int b = blockIdx.z, mt = blockIdx.y, n0 = blockIdx.x * 112;
  const int tid = threadIdx.x, lane = tid & 63, wave = tid >> 6;
  const int lm = lane & 15, lq = lane >> 4;
  __shared__ __align__(16) u16 Bl[112 * 40];
  f32x4 zf = {0.f, 0.f, 0.f, 0.f};
  f32x4 acc[7];
#pragma unroll
  for (int t = 0; t < 7; ++t) acc[t] = zf;
  const u16* Bb = xT + ((size_t)b * 784 + n0) * 512;
  const u16* Ar = W + (size_t)(mt * 64 + wave * 16 + lm) * 512;
  for (int ks = 0; ks < 16; ++ks) {
    __syncthreads();
    for (int u = tid; u < 448; u += 256) {
      int row = u >> 2, seg = u & 3;
      int4 v = *reinterpret_cast<const int4*>(Bb + (size_t)row * 512 + ks * 32 + seg * 8);
      *reinterpret_cast<int4*>(&Bl[row * 40 + seg * 8]) = v;
    }
    __syncthreads();
    bf16x8 af = ld_bf8(Ar + ks * 32 + lq * 8);
#pragma unroll
    for (int t = 0; t < 7; ++t) {
      bf16x8 bf8 = ld_bf8(&Bl[(t * 16 + lm) * 40 + lq * 8]);
      acc[t] = MFMA16(af, bf8, acc[t]);
    }
  }
  const int og = mt * 64 + wave * 16 + lq * 4;
  float sc[4], bi[4];
#pragma unroll
  for (int r = 0; r < 4; ++r) { sc[r] = gq[og + r] * INVS; bi[r] = bq[og + r]; }
  const int g = og >> 7, r128 = og & 127;
  const size_t bg = (size_t)b * 8 + g;
#pragma unroll
  for (int t = 0; t < 7; ++t) {
    int j = n0 + t * 16 + lm;
    u16 h[4];
#pragma unroll
    for (int r = 0; r < 4; ++r) h[r] = f2bf(acc[t][r] * sc[r] + bi[r]);
    if (r128 < 64) {
      u16* dst = (r128 < 32) ? Qs : Ks;
      int c = r128 & 31;
      u32 lo = (u32)h[0] | ((u32)h[1] << 16);
      u32 hi = (u32)h[2] | ((u32)h[3] << 16);
      *reinterpret_cast<int2*>(dst + (bg * 784 + j) * 32 + c) = make_int2((int)lo, (int)hi);
    } else {
      int c = r128 - 64;
#pragma unroll
      for (int r = 0; r < 4; ++r) Vs[(bg * 64 + c + r) * 784 + j] = h[r];
    }
  }
}

// ---------------- grouped 3x3 conv via 9 shifted MFMA passes ----------------
__global__ __launch_bounds__(256) void k_conv1(const u16* __restrict__ xT,
                                               const u16* __restrict__ W1t,
                                               u16* __restrict__ umid) {
  const int b = blockIdx.z, g = blockIdx.y, n0 = blockIdx.x * 112;
  const int tid = threadIdx.x, lane = tid & 63, wave = tid >> 6;
  const int lm = lane & 15, lq = lane >> 4;
  __shared__ __align__(16) u16 xl[170 * 72];
  for (int u = tid; u < 1360; u += 256) {
    int row = u >> 3, seg = u & 7;
    int ng = n0 - 29 + row;
    int4 v = {0, 0, 0, 0};
    if (ng >= 0 && ng < 784)
      v = *reinterpret_cast<const int4*>(xT + ((size_t)b * 784 + ng) * 512 + g * 64 + seg * 8);
    *reinterpret_cast<int4*>(&xl[row * 72 + seg * 8]) = v;
  }
  __syncthreads();
  f32x4 zf = {0.f, 0.f, 0.f, 0.f};
  f32x4 acc[7];
#pragma unroll
  for (int t = 0; t < 7; ++t) acc[t] = zf;
  const u16* Wg = W1t + (size_t)g * 9 * 4096;
#pragma unroll
  for (int k9 = 0; k9 < 9; ++k9) {
    const int dh = k9 / 3 - 1, dw = k9 % 3 - 1;
#pragma unroll
    for (int ks = 0; ks < 2; ++ks) {
      bf16x8 af = ld_bf8(Wg + (k9 * 64 + wave * 16 + lm) * 64 + ks * 32 + lq * 8);
#pragma unroll
      for (int t = 0; t < 7; ++t) {
        int n = n0 + t * 16 + lm;
        int ww = n % 28 + dw;
        bf16x8 bf8;
        if (ww >= 0 && ww < 28)
          bf8 = ld_bf8(&xl[(t * 16 + lm + dh * 28 + dw + 29) * 72 + ks * 32 + lq * 8]);
        else
          bf8 = zero8();
        acc[t] = MFMA16(af, bf8, acc[t]);
      }
    }
  }
  const int oc4 = g * 64 + wave * 16 + lq * 4;
#pragma unroll
  for (int t = 0; t < 7; ++t) {
    int j = n0 + t * 16 + lm;
    u16 h[4];
#pragma unroll
    for (int r = 0; r < 4; ++r) h[r] = f2bf(acc[t][r]);
    u32 lo = (u32)h[0] | ((u32)h[1] << 16);
    u32 hi = (u32)h[2] | ((u32)h[3] << 16);
    *reinterpret_cast<int2*>(umid + ((size_t)b * 784 + j) * 512 + oc4) = make_int2((int)lo, (int)hi);
  }
}

// ---------------- xw2 1x1 GEMM + bn -> unaryT32 (b,784,512) f32 ----------------
__global__ __launch_bounds__(256) void k_gemm_x2(
    const u16* __restrict__ W, const u16* __restrict__ Bsrc,
    const float* __restrict__ gv, const float* __restrict__ bv,
    float* __restrict__ outT) {
  const int b = blockIdx.z, mt = blockIdx.y, n0 = blockIdx.x * 112;
  const int tid = threadIdx.x, lane = tid & 63, wave = tid >> 6;
  const int lm = lane & 15, lq = lane >> 4;
  __shared__ __align__(16) u16 Bl[112 * 40];
  f32x4 zf = {0.f, 0.f, 0.f, 0.f};
  f32x4 acc[7];
#pragma unroll
  for (int t = 0; t < 7; ++t) acc[t] = zf;
  const u16* Bb = Bsrc + ((size_t)b * 784 + n0) * 512;
  const u16* Ar = W + (size_t)(mt * 64 + wave * 16 + lm) * 512;
  for (int ks = 0; ks < 16; ++ks) {
    __syncthreads();
    for (int u = tid; u < 448; u += 256) {
      int row = u >> 2, seg = u & 3;
      int4 v = *reinterpret_cast<const int4*>(Bb + (size_t)row * 512 + ks * 32 + seg * 8);
      *reinterpret_cast<int4*>(&Bl[row * 40 + seg * 8]) = v;
    }
    __syncthreads();
    bf16x8 af = ld_bf8(Ar + ks * 32 + lq * 8);
#pragma unroll
    for (int t = 0; t < 7; ++t) {
      bf16x8 bf8 = ld_bf8(&Bl[(t * 16 + lm) * 40 + lq * 8]);
      acc[t] = MFMA16(af, bf8, acc[t]);
    }
  }
  const int og = mt * 64 + wave * 16 + lq * 4;
  float sc[4], bi[4];
#pragma unroll
  for (int r = 0; r < 4; ++r) { sc[r] = gv[og + r] * INVS; bi[r] = bv[og + r]; }
#pragma unroll
  for (int t = 0; t < 7; ++t) {
    int j = n0 + t * 16 + lm;
    float4 o4;
    o4.x = acc[t][0] * sc[0] + bi[0];
    o4.y = acc[t][1] * sc[1] + bi[1];
    o4.z = acc[t][2] * sc[2] + bi[2];
    o4.w = acc[t][3] * sc[3] + bi[3];
    *reinterpret_cast<float4*>(outT + ((size_t)b * 784 + j) * 512 + og) = o4;
  }
}

// ---------------- fused attention per (b, g, 16-row i-tile) ----------------
// R3: logits in registers L[13][4]; P~ bf16 in Pl[16][840] (u16, word-stride
// 420 -> 16B-aligned rows, 2-way-max banks); register softmax via shfl +
// 64-float cross-wave LDS; pads [0,16)+[800,840) zeroed for guard-free Psh gather.
__global__ __launch_bounds__(256, 4) void k_attn(
    const u16* __restrict__ Qs, const u16* __restrict__ Ks, const u16* __restrict__ Vs,
    const u16* __restrict__ relq, const u16* __restrict__ relk, const u16* __restrict__ relv,
    const float* __restrict__ g_sim, const float* __restrict__ g_out,
    const float* __restrict__ b_out, float* __restrict__ binT) {
  const int b = blockIdx.z, g = blockIdx.y, i0 = blockIdx.x * 16;
  const int tid = threadIdx.x, lane = tid & 63, wave = tid >> 6;
  const int lm = lane & 15, lq = lane >> 4;
  __shared__ __align__(16) u16 Pl[16 * 840];      // bf16 P~, row stride 840
  __shared__ __align__(16) float KRs[4][16][34];  // per-wave KR band tile
  __shared__ float WM[4][16];                     // per-wave row max
  __shared__ float WS[4][16];                     // per-wave row sum
  u32* PlW = reinterpret_cast<u32*>(Pl);
  // zero pads: word cols [0,8) and [400,420) of each row
  for (int u = tid; u < 448; u += 256) {
    int r = u / 28, c = u % 28;
    PlW[r * 420 + (c < 8 ? c : 392 + c)] = 0;
  }
  const float s0 = g_sim[g] * INVS, s1 = g_sim[8 + g] * INVS, s2 = g_sim[16 + g] * INVS;
  const size_t bg = (size_t)b * 8 + g;
  const u16* Qb = Qs + bg * 784 * 32;
  const u16* Kb = Ks + bg * 784 * 32;
  const u16* Vb = Vs + bg * 64 * 784;
  const bf16x8 aq = ld_bf8(Qb + (i0 + lm) * 32 + lq * 8);
  const f32x4 zf = {0.f, 0.f, 0.f, 0.f};
  // ---- phase 1: logits into registers; wave owns j-tiles wave, wave+4, ... ----
  float L[13][4];
  float vmax[4] = {-1e30f, -1e30f, -1e30f, -1e30f};
  bf16x8 kfc, bq0c, bq1c, bk0c, bk1c;
  {
    const int j0 = wave * 16;
    const int d0 = 768 + i0 - j0, e0 = 768 + j0 - i0;
    kfc = ld_bf8(Kb + (j0 + lm) * 32 + lq * 8);
    bq0c = ld_bf8(relq + (d0 + lm) * 32 + lq * 8);
    bq1c = ld_bf8(relq + (d0 + 16 + lm) * 32 + lq * 8);
    bk0c = ld_bf8(relk + (e0 + lm) * 32 + lq * 8);
    bk1c = ld_bf8(relk + (e0 + 16 + lm) * 32 + lq * 8);
  }
  int jt = wave;
#pragma unroll
  for (int rr = 0; rr < 13; ++rr) {
    const int jtn = jt + 4;
    bf16x8 kfn = kfc, bq0n = bq0c, bq1n = bq1c, bk0n = bk0c, bk1n = bk1c;
    if (jtn < 49) {
      const int j0n = jtn * 16;
      const int d0 = 768 + i0 - j0n, e0 = 768 + j0n - i0;
      kfn = ld_bf8(Kb + (j0n + lm) * 32 + lq * 8);
      bq0n = ld_bf8(relq + (d0 + lm) * 32 + lq * 8);
      bq1n = ld_bf8(relq + (d0 + 16 + lm) * 32 + lq * 8);
      bk0n = ld_bf8(relk + (e0 + lm) * 32 + lq * 8);
      bk1n = ld_bf8(relk + (e0 + 16 + lm) * 32 + lq * 8);
    }
    if (jt < 49) {
      f32x4 aqk = MFMA16(aq, kfc, zf);      // qk[i][j]
      f32x4 q0 = MFMA16(aq, bq0c, zf);      // QRt[i][d] cols 0..15
      f32x4 q1 = MFMA16(aq, bq1c, zf);      // cols 16..31
      f32x4 k0 = MFMA16(kfc, bk0c, zf);     // KRt[j][s] cols 0..15
      f32x4 k1 = MFMA16(kfc, bk1c, zf);
#pragma unroll
      for (int r = 0; r < 4; ++r) {
        int m = lq * 4 + r;
        KRs[wave][m][lm] = k0[r];
        KRs[wave][m][16 + lm] = k1[r];
      }
      // per-wave LDS RAW: compiler inserts lgkmcnt wait, no barrier needed
#pragma unroll
      for (int r = 0; r < 4; ++r) {
        int m = lq * 4 + r, n = lm;
        int c = m - n + 15;  // qr gather col
        int srcl = (c & 15) | (lane & 48);
        float t0 = bpermf(q0[r], srcl), t1 = bpermf(q1[r], srcl);
        float qv = (c & 16) ? t1 : t0;
        float kv = KRs[wave][n][n - m + 15];
        float val = aqk[r] * s0 + qv * s1 + kv * s2;  // b_sim drops (shift-invariant)
        vmax[r] = fmaxf(vmax[r], val);
        L[rr][r] = val;
      }
    }
    jt = jtn;
    kfc = kfn; bq0c = bq0n; bq1c = bq1n; bk0c = bk0n; bk1c = bk1n;
  }
  // ---- phase 2: register softmax ----
#pragma unroll
  for (int r = 0; r < 4; ++r) {
#pragma unroll
    for (int d = 1; d < 16; d <<= 1) vmax[r] = fmaxf(vmax[r], __shfl_xor(vmax[r], d, 64));
  }
  if (lm == 0) {
#pragma unroll
    for (int r = 0; r < 4; ++r) WM[wave][lq * 4 + r] = vmax[r];
  }
  __syncthreads();
  float gmax[4], rsum[4] = {0.f, 0.f, 0.f, 0.f};
#pragma unroll
  for (int r = 0; r < 4; ++r) {
    int m = lq * 4 + r;
    gmax[r] = fmaxf(fmaxf(WM[0][m], WM[1][m]), fmaxf(WM[2][m], WM[3][m]));
  }
  const bool evlm = (lm & 1) == 0;
  int jt2 = wave;
#pragma unroll
  for (int rr = 0; rr < 13; ++rr) {
    if (jt2 < 49) {
#pragma unroll
      for (int r = 0; r < 4; ++r) {
        float e = __expf(L[rr][r] - gmax[r]);
        rsum[r] += e;
        u32 own = (u32)f2bf(e);
        u32 oth = (u32)__shfl_xor((int)own, 1, 64);
        if (evlm) {
          int m = lq * 4 + r;
          PlW[m * 420 + 8 + jt2 * 8 + (lm >> 1)] = own | (oth << 16);
        }
      }
    }
    jt2 += 4;
  }
#pragma unroll
  for (int r = 0; r < 4; ++r) {
#pragma unroll
    for (int d = 1; d < 16; d <<= 1) rsum[r] += __shfl_xor(rsum[r], d, 64);
  }
  if (lm == 0) {
#pragma unroll
    for (int r = 0; r < 4; ++r) WS[wave][lq * 4 + r] = rsum[r];
  }
  __syncthreads();
  // ---- phase 3: PV; wave = c-chunk of 16; sv = P~ @ V^T, sve = Psh @ relv^T ----
  f32x4 accV = zf, accE = zf;
  const int coff = wave * 16;
  const u16* Vr = Vb + (size_t)(coff + lm) * 784;
  const u16* Rr = relv + (size_t)(coff + lm) * 1600 + i0;
  const u16* Prow = &Pl[lm * 840];
  for (int ks = 0; ks < 25; ++ks) {
    bf16x8 ap = ld_bf8(Prow + 16 + ks * 32 + lq * 8);
    bf16x8 bv = ld_bf8(Vr + ks * 32 + lq * 8);
    accV = MFMA16(ap, bv, accV);
    const int base = 799 + lm - ks * 32 - lq * 8;  // padded col for e=0
    u16 h[8];
#pragma unroll
    for (int e = 0; e < 8; ++e) h[e] = Prow[base - e];  // Psh, pads give 0
    bf16x8 ash = pack8(h);
    bf16x8 br = ld_bf8(Rr + ks * 32 + lq * 8);
    accE = MFMA16(ash, br, accE);
  }
  // ---- epilogue: binary[b, g*64+c, i] = bn(sv)+bn(sve), write (i, c) layout ----
  const int c = coff + lm;
  const int oi = g * 128 + 2 * c;
  const float so0 = g_out[oi] * INVS, bo0 = b_out[oi];
  const float so1 = g_out[oi + 1] * INVS, bo1 = b_out[oi + 1];
#pragma unroll
  for (int r = 0; r < 4; ++r) {
    int row = lq * 4 + r;
    float rl = 1.0f / (WS[0][row] + WS[1][row] + WS[2][row] + WS[3][row]);
    float val = accV[r] * rl * so0 + bo0 + accE[r] * rl * so1 + bo1;
    binT[((size_t)b * 784 + i0 + row) * 512 + g * 64 + c] = val;
  }
}

// ---------------- rw GEMM: relu(concat(unary,binary)) -> relu(bn) -> rT bf16 ----------------
__global__ __launch_bounds__(256) void k_gemm_rw(
    const u16* __restrict__ W, const float* __restrict__ unT, const float* __restrict__ binT,
    const float* __restrict__ gv, const float* __restrict__ bv, u16* __restrict__ rT) {
  const int b = blockIdx.z, mt = blockIdx.y, n0 = blockIdx.x * 112;
  const int tid = threadIdx.x, lane = tid & 63, wave = tid >> 6;
  const int lm = lane & 15, lq = lane >> 4;
  __shared__ __align__(16) u16 Bl[112 * 40];
  f32x4 zf = {0.f, 0.f, 0.f, 0.f};
  f32x4 acc[7];
#pragma unroll
  for (int t = 0; t < 7; ++t) acc[t] = zf;
  const u16* Ar = W + (size_t)(mt * 64 + wave * 16 + lm) * 1024;
  for (int ks = 0; ks < 32; ++ks) {
    __syncthreads();
    const float* src_base = (ks < 16) ? unT : binT;
    const int k0 = (ks & 15) * 32;
    for (int u = tid; u < 448; u += 256) {
      int row = u >> 2, seg = u & 3;
      const float* sp = src_base + ((size_t)b * 784 + n0 + row) * 512 + k0 + seg * 8;
      float4 v0 = *reinterpret_cast<const float4*>(sp);
      float4 v1 = *reinterpret_cast<const float4*>(sp + 4);
      u16 h[8] = {f2bf(fmaxf(v0.x, 0.f)), f2bf(fmaxf(v0.y, 0.f)),
                  f2bf(fmaxf(v0.z, 0.f)), f2bf(fmaxf(v0.w, 0.f)),
                  f2bf(fmaxf(v1.x, 0.f)), f2bf(fmaxf(v1.y, 0.f)),
                  f2bf(fmaxf(v1.z, 0.f)), f2bf(fmaxf(v1.w, 0.f))};
      *reinterpret_cast<int4*>(&Bl[row * 40 + seg * 8]) = __builtin_bit_cast(int4, pack8(h));
    }
    __syncthreads();
    bf16x8 af = ld_bf8(Ar + ks * 32 + lq * 8);
#pragma unroll
    for (int t = 0; t < 7; ++t) {
      bf16x8 bf8 = ld_bf8(&Bl[(t * 16 + lm) * 40 + lq * 8]);
      acc[t] = MFMA16(af, bf8, acc[t]);
    }
  }
  const int og = mt * 64 + wave * 16 + lq * 4;
  float sc[4], bi[4];
#pragma unroll
  for (int r = 0; r < 4; ++r) { sc[r] = gv[og + r] * INVS; bi[r] = bv[og + r]; }
#pragma unroll
  for (int t = 0; t < 7; ++t) {
    int j = n0 + t * 16 + lm;
    u16 h[4];
#pragma unroll
    for (int r = 0; r < 4; ++r) h[r] = f2bf(fmaxf(acc[t][r] * sc[r] + bi[r], 0.f));
    u32 lo = (u32)h[0] | ((u32)h[1] << 16);
    u32 hi = (u32)h[2] | ((u32)h[3] << 16);
    *reinterpret_cast<int2*>(rT + ((size_t)b * 784 + j) * 512 + og) = make_int2((int)lo, (int)hi);
  }
}

// ---------------- pw GEMM + sigmoid gate + final fuse -> d_out ----------------
__global__ __launch_bounds__(256) void k_gemm_pw(
    const u16* __restrict__ W, const u16* __restrict__ rT,
    const float* __restrict__ gv, const float* __restrict__ bv,
    const float* __restrict__ binT, const float* __restrict__ unT,
    float* __restrict__ out) {
  const int b = blockIdx.z, mt = blockIdx.y, n0 = blockIdx.x * 112;
  const int tid = threadIdx.x, lane = tid & 63, wave = tid >> 6;
  const int lm = lane & 15, lq = lane >> 4;
  __shared__ __align__(16) u16 Bl[112 * 40];
  f32x4 zf = {0.f, 0.f, 0.f, 0.f};
  f32x4 acc[7];
#pragma unroll
  for (int t = 0; t < 7; ++t) acc[t] = zf;
  const u16* Bb = rT + ((size_t)b * 784 + n0) * 512;
  const u16* Ar = W + (size_t)(mt * 64 + wave * 16 + lm) * 512;
  for (int ks = 0; ks < 16; ++ks) {
    __syncthreads();
    for (int u = tid; u < 448; u += 256) {
      int row = u >> 2, seg = u & 3;
      int4 v = *reinterpret_cast<const int4*>(Bb + (size_t)row * 512 + ks * 32 + seg * 8);
      *reinterpret_cast<int4*>(&Bl[row * 40 + seg * 8]) = v;
    }
    __syncthreads();
    bf16x8 af = ld_bf8(Ar + ks * 32 + lq * 8);
#pragma unroll
    for (int t = 0; t < 7; ++t) {
      bf16x8 bf8 = ld_bf8(&Bl[(t * 16 + lm) * 40 + lq * 8]);
      acc[t] = MFMA16(af, bf8, acc[t]);
    }
  }
  const int og = mt * 64 + wave * 16 + lq * 4;
  float sc[4], bi[4];
#pragma unroll
  for (int r = 0; r < 4; ++r) { sc[r] = gv[og + r] * INVS; bi[r] = bv[og + r]; }
#pragma unroll
  for (int t = 0; t < 7; ++t) {
    int j = n0 + t * 16 + lm;
    float4 bin4 = *reinterpret_cast<const float4*>(binT + ((size_t)b * 784 + j) * 512 + og);
    float4 un4 = *reinterpret_cast<const float4*>(unT + ((size_t)b * 784 + j) * 512 + og);
    float binv[4] = {bin4.x, bin4.y, bin4.z, bin4.w};
    float unv[4] = {un4.x, un4.y, un4.z, un4.w};
#pragma unroll
    for (int r = 0; r < 4; ++r) {
      float gt = 1.f / (1.f + __expf(-(acc[t][r] * sc[r] + bi[r])));
      out[((size_t)b * 512 + og + r) * 784 + j] = gt * binv[r] + unv[r];
    }
  }
}

extern "C" void kernel_launch(void* const* d_in, const int* in_sizes, int n_in,
                              void* d_out, int out_size, void* d_ws, size_t ws_size,
                              hipStream_t stream) {
  const float* x = (const float*)d_in[0];
  const float* qkv_w = (const float*)d_in[1];
  const float* g_qkv = (const float*)d_in[2];
  const float* b_qkv = (const float*)d_in[3];
  const float* g_sim = (const float*)d_in[4];
  // d_in[5] = b_sim: unused (softmax is shift-invariant per (b,g) row)
  const float* g_out = (const float*)d_in[6];
  const float* b_out = (const float*)d_in[7];
  const float* relative = (const float*)d_in[8];
  const float* xw1 = (const float*)d_in[9];
  const float* xw2 = (const float*)d_in[10];
  const float* g_x = (const float*)d_in[11];
  const float* b_x = (const float*)d_in[12];
  const float* rw = (const float*)d_in[13];
  const float* g_r = (const float*)d_in[14];
  const float* b_r = (const float*)d_in[15];
  const float* pw = (const float*)d_in[16];
  const float* g_p = (const float*)d_in[17];
  const float* b_p = (const float*)d_in[18];

  char* p = (char*)d_ws;
  auto take = [&](size_t n) { char* q = p; p += (n + 255) & ~(size_t)255; return q; };
  u16* xT = (u16*)take((size_t)8 * 784 * 512 * 2);
  u16* Wq = (u16*)take((size_t)1024 * 512 * 2);
  u16* W2 = (u16*)take((size_t)512 * 512 * 2);
  u16* Wr = (u16*)take((size_t)512 * 1024 * 2);
  u16* Wp = (u16*)take((size_t)512 * 512 * 2);
  u16* W1t = (u16*)take((size_t)294912 * 2);
  u16* relq = (u16*)take((size_t)51200 * 2);
  u16* relk = (u16*)take((size_t)51200 * 2);
  u16* relv = (u16*)take((size_t)102400 * 2);
  u16* Qs = (u16*)take((size_t)8 * 8 * 784 * 32 * 2);
  u16* Ks = (u16*)take((size_t)8 * 8 * 784 * 32 * 2);
  u16* Vs = (u16*)take(((size_t)8 * 8 * 64 * 784 + 64) * 2);  // +64 pad for K=800 reads
  u16* umid = (u16*)take((size_t)8 * 784 * 512 * 2);
  float* unT = (float*)take((size_t)8 * 784 * 512 * 4);
  float* binT = (float*)take((size_t)8 * 784 * 512 * 4);
  u16* rT = (u16*)take((size_t)8 * 784 * 512 * 2);

  k_prep<<<dim3(8096), dim3(256), 0, stream>>>(qkv_w, xw2, rw, pw, xw1, relative,
                                               Wq, W2, Wr, Wp, W1t, relq, relk, relv);
  k_transpose<<<dim3(25, 8, 8), dim3(256), 0, stream>>>(x, xT);
  k_gemm_qkv<<<dim3(7, 16, 8), dim3(256), 0, stream>>>(Wq, xT, g_qkv, b_qkv, Qs, Ks, Vs);
  k_conv1<<<dim3(7, 8, 8), dim3(256), 0, stream>>>(xT, W1t, umid);
  k_gemm_x2<<<dim3(7, 8, 8), dim3(256), 0, stream>>>(W2, umid, g_x, b_x, unT);
  k_attn<<<dim3(49, 8, 8), dim3(256), 0, stream>>>(Qs, Ks, Vs, relq, relk, relv,
                                                   g_sim, g_out, b_out, binT);
  k_gemm_rw<<<dim3(7, 8, 8), dim3(256), 0, stream>>>(Wr, unT, binT, g_r, b_r, rT);
  k_gemm_pw<<<dim3(7, 8, 8), dim3(256), 0, stream>>>(Wp, rT, g_p, b_p, binT, unT,
                                                     (float*)d_out);
}

// Round 4
// 335.725 us; speedup vs baseline: 1.4750x; 1.4750x over previous
//
#include <hip/hip_runtime.h>
#include <math.h>

// LESA block for MI355X. N=8, C=512, H=W=28 (HW=784), G=8, QKP=32, VP=64, BP=512.
// All GEMM-shaped math in bf16 MFMA (16x16x32), softmax/bn/epilogues fp32.
// R4: k_attn — R2 skeleton (88 VGPR, no spills) + fp16 logits in LDS (28KB vs
// 54KB fp32) converted IN-PLACE to bf16 P~ during softmax; PV reads bf16
// directly (no f2bf in loop). LDS ~37KB -> 4 blocks/CU (vs 2).

typedef unsigned short u16;
typedef unsigned int u32;
typedef __bf16 bf16x8 __attribute__((ext_vector_type(8)));
typedef float f32x4 __attribute__((ext_vector_type(4)));

#define INVS 0.99999500003749968f  // 1/sqrt(1+1e-5)
#define MFMA16(a, b, c) __builtin_amdgcn_mfma_f32_16x16x32_bf16(a, b, c, 0, 0, 0)

__device__ inline u16 f2bf(float f) {
  u32 u = __builtin_bit_cast(u32, f);
  return (u16)((u + 0x7fffu + ((u >> 16) & 1u)) >> 16);
}
__device__ inline bf16x8 ld_bf8(const u16* p) {
  int4 v = *reinterpret_cast<const int4*>(p);
  return __builtin_bit_cast(bf16x8, v);
}
__device__ inline bf16x8 pack8(const u16 h[8]) {
  int4 v;
  v.x = (int)((u32)h[0] | ((u32)h[1] << 16));
  v.y = (int)((u32)h[2] | ((u32)h[3] << 16));
  v.z = (int)((u32)h[4] | ((u32)h[5] << 16));
  v.w = (int)((u32)h[6] | ((u32)h[7] << 16));
  return __builtin_bit_cast(bf16x8, v);
}
__device__ inline bf16x8 zero8() {
  int4 z = {0, 0, 0, 0};
  return __builtin_bit_cast(bf16x8, z);
}
__device__ inline float bpermf(float v, int srcl) {
  return __builtin_bit_cast(float,
      __builtin_amdgcn_ds_bpermute(srcl << 2, __builtin_bit_cast(int, v)));
}

// ---------------- prep: weight casts/permutes + relative tables ----------------
__global__ __launch_bounds__(256) void k_prep(
    const float* __restrict__ qkv_w, const float* __restrict__ xw2,
    const float* __restrict__ rw, const float* __restrict__ pw,
    const float* __restrict__ xw1, const float* __restrict__ rel,
    u16* __restrict__ Wq, u16* __restrict__ W2, u16* __restrict__ Wr,
    u16* __restrict__ Wp, u16* __restrict__ W1t, u16* __restrict__ relq,
    u16* __restrict__ relk, u16* __restrict__ relv) {
  int idx = blockIdx.x * 256 + threadIdx.x;
  if (idx < 524288) { Wq[idx] = f2bf(qkv_w[idx]); return; }
  idx -= 524288;
  if (idx < 262144) { W2[idx] = f2bf(xw2[idx]); return; }
  idx -= 262144;
  if (idx < 524288) { Wr[idx] = f2bf(rw[idx]); return; }
  idx -= 524288;
  if (idx < 262144) { Wp[idx] = f2bf(pw[idx]); return; }
  idx -= 262144;
  if (idx < 294912) {  // W1t[(g*9+k9)*64 + oc][ic] = xw1[g*64+oc][ic][kh][kw]
    int gk = idx >> 12, rem = idx & 4095, oc = rem >> 6, ic = rem & 63;
    int g = gk / 9, k9 = gk % 9;
    W1t[idx] = f2bf(xw1[(((g * 64 + oc) * 64) + ic) * 9 + k9]);
    return;
  }
  idx -= 294912;
  if (idx < 51200) {  // relq[t][c] = relative[c][t], t<1600 (pad 0)
    int t = idx >> 5, c = idx & 31;
    relq[idx] = (t < 1567) ? f2bf(rel[c * 1567 + t]) : (u16)0;
    return;
  }
  idx -= 51200;
  if (idx < 51200) {
    int t = idx >> 5, c = idx & 31;
    relk[idx] = (t < 1567) ? f2bf(rel[(32 + c) * 1567 + t]) : (u16)0;
    return;
  }
  idx -= 51200;
  if (idx < 102400) {  // relv[c][t] (c<64, t<1600 pad 0)
    int c = idx / 1600, t = idx % 1600;
    relv[idx] = (t < 1567) ? f2bf(rel[(64 + c) * 1567 + t]) : (u16)0;
    return;
  }
}

// ---------------- transpose x (b,512,784) f32 -> xT (b,784,512) bf16 ----------------
__global__ __launch_bounds__(256) void k_transpose(const float* __restrict__ x,
                                                   u16* __restrict__ xT) {
  const int b = blockIdx.z, c0 = blockIdx.y * 64, n0 = blockIdx.x * 32;
  const int tid = threadIdx.x;
  __shared__ __align__(16) u16 tl[64][36];
#pragma unroll
  for (int h = 0; h < 2; ++h) {
    int cl = (tid >> 3) + h * 32;
    int n4 = (tid & 7) * 4;
    float4 v = {0.f, 0.f, 0.f, 0.f};
    if (n0 + n4 + 3 < 784)
      v = *reinterpret_cast<const float4*>(x + ((size_t)b * 512 + c0 + cl) * 784 + n0 + n4);
    u32 lo = (u32)f2bf(v.x) | ((u32)f2bf(v.y) << 16);
    u32 hi = (u32)f2bf(v.z) | ((u32)f2bf(v.w) << 16);
    *reinterpret_cast<int2*>(&tl[cl][n4]) = make_int2((int)lo, (int)hi);
  }
  __syncthreads();
  int nl = tid >> 3, c8 = (tid & 7) * 8;
  if (n0 + nl < 784) {
    u16 h[8];
#pragma unroll
    for (int e = 0; e < 8; ++e) h[e] = tl[c8 + e][nl];
    *reinterpret_cast<int4*>(xT + ((size_t)b * 784 + n0 + nl) * 512 + c0 + c8) =
        __builtin_bit_cast(int4, pack8(h));
  }
}

// ---------------- qkv GEMM: (1024x512)@(512x784) + bn -> Q,K (j,c) / V (c,j) bf16 ----------------
__global__ __launch_bounds__(256) void k_gemm_qkv(
    const u16* __restrict__ W, const u16* __restrict__ xT,
    const float* __restrict__ gq, const float* __restrict__ bq,
    u16* __restrict__ Qs, u16* __restrict__ Ks, u16* __restrict__ Vs) {
  const int b = blockIdx.z, mt = blockIdx.y, n0 = blockIdx.x * 112;
  const int tid = threadIdx.x, lane = tid & 63, wave = tid >> 6;
  const int lm = lane & 15, lq = lane >> 4;
  __shared__ __align__(16) u16 Bl[112 * 40];
  f32x4 zf = {0.f, 0.f, 0.f, 0.f};
  f32x4 acc[7];
#pragma unroll
  for (int t = 0; t < 7; ++t) acc[t] = zf;
  const u16* Bb = xT + ((size_t)b * 784 + n0) * 512;
  const u16* Ar = W + (size_t)(mt * 64 + wave * 16 + lm) * 512;
  for (int ks = 0; ks < 16; ++ks) {
    __syncthreads();
    for (int u = tid; u < 448; u += 256) {
      int row = u >> 2, seg = u & 3;
      int4 v = *reinterpret_cast<const int4*>(Bb + (size_t)row * 512 + ks * 32 + seg * 8);
      *reinterpret_cast<int4*>(&Bl[row * 40 + seg * 8]) = v;
    }
    __syncthreads();
    bf16x8 af = ld_bf8(Ar + ks * 32 + lq * 8);
#pragma unroll
    for (int t = 0; t < 7; ++t) {
      bf16x8 bf8 = ld_bf8(&Bl[(t * 16 + lm) * 40 + lq * 8]);
      acc[t] = MFMA16(af, bf8, acc[t]);
    }
  }
  const int og = mt * 64 + wave * 16 + lq * 4;
  float sc[4], bi[4];
#pragma unroll
  for (int r = 0; r < 4; ++r) { sc[r] = gq[og + r] * INVS; bi[r] = bq[og + r]; }
  const int g = og >> 7, r128 = og & 127;
  const size_t bg = (size_t)b * 8 + g;
#pragma unroll
  for (int t = 0; t < 7; ++t) {
    int j = n0 + t * 16 + lm;
    u16 h[4];
#pragma unroll
    for (int r = 0; r < 4; ++r) h[r] = f2bf(acc[t][r] * sc[r] + bi[r]);
    if (r128 < 64) {
      u16* dst = (r128 < 32) ? Qs : Ks;
      int c = r128 & 31;
      u32 lo = (u32)h[0] | ((u32)h[1] << 16);
      u32 hi = (u32)h[2] | ((u32)h[3] << 16);
      *reinterpret_cast<int2*>(dst + (bg * 784 + j) * 32 + c) = make_int2((int)lo, (int)hi);
    } else {
      int c = r128 - 64;
#pragma unroll
      for (int r = 0; r < 4; ++r) Vs[(bg * 64 + c + r) * 784 + j] = h[r];
    }
  }
}

// ---------------- grouped 3x3 conv via 9 shifted MFMA passes ----------------
__global__ __launch_bounds__(256) void k_conv1(const u16* __restrict__ xT,
                                               const u16* __restrict__ W1t,
                                               u16* __restrict__ umid) {
  const int b = blockIdx.z, g = blockIdx.y, n0 = blockIdx.x * 112;
  const int tid = threadIdx.x, lane = tid & 63, wave = tid >> 6;
  const int lm = lane & 15, lq = lane >> 4;
  __shared__ __align__(16) u16 xl[170 * 72];
  for (int u = tid; u < 1360; u += 256) {
    int row = u >> 3, seg = u & 7;
    int ng = n0 - 29 + row;
    int4 v = {0, 0, 0, 0};
    if (ng >= 0 && ng < 784)
      v = *reinterpret_cast<const int4*>(xT + ((size_t)b * 784 + ng) * 512 + g * 64 + seg * 8);
    *reinterpret_cast<int4*>(&xl[row * 72 + seg * 8]) = v;
  }
  __syncthreads();
  f32x4 zf = {0.f, 0.f, 0.f, 0.f};
  f32x4 acc[7];
#pragma unroll
  for (int t = 0; t < 7; ++t) acc[t] = zf;
  const u16* Wg = W1t + (size_t)g * 9 * 4096;
#pragma unroll
  for (int k9 = 0; k9 < 9; ++k9) {
    const int dh = k9 / 3 - 1, dw = k9 % 3 - 1;
#pragma unroll
    for (int ks = 0; ks < 2; ++ks) {
      bf16x8 af = ld_bf8(Wg + (k9 * 64 + wave * 16 + lm) * 64 + ks * 32 + lq * 8);
#pragma unroll
      for (int t = 0; t < 7; ++t) {
        int n = n0 + t * 16 + lm;
        int ww = n % 28 + dw;
        bf16x8 bf8;
        if (ww >= 0 && ww < 28)
          bf8 = ld_bf8(&xl[(t * 16 + lm + dh * 28 + dw + 29) * 72 + ks * 32 + lq * 8]);
        else
          bf8 = zero8();
        acc[t] = MFMA16(af, bf8, acc[t]);
      }
    }
  }
  const int oc4 = g * 64 + wave * 16 + lq * 4;
#pragma unroll
  for (int t = 0; t < 7; ++t) {
    int j = n0 + t * 16 + lm;
    u16 h[4];
#pragma unroll
    for (int r = 0; r < 4; ++r) h[r] = f2bf(acc[t][r]);
    u32 lo = (u32)h[0] | ((u32)h[1] << 16);
    u32 hi = (u32)h[2] | ((u32)h[3] << 16);
    *reinterpret_cast<int2*>(umid + ((size_t)b * 784 + j) * 512 + oc4) = make_int2((int)lo, (int)hi);
  }
}

// ---------------- xw2 1x1 GEMM + bn -> unaryT32 (b,784,512) f32 ----------------
__global__ __launch_bounds__(256) void k_gemm_x2(
    const u16* __restrict__ W, const u16* __restrict__ Bsrc,
    const float* __restrict__ gv, const float* __restrict__ bv,
    float* __restrict__ outT) {
  const int b = blockIdx.z, mt = blockIdx.y, n0 = blockIdx.x * 112;
  const int tid = threadIdx.x, lane = tid & 63, wave = tid >> 6;
  const int lm = lane & 15, lq = lane >> 4;
  __shared__ __align__(16) u16 Bl[112 * 40];
  f32x4 zf = {0.f, 0.f, 0.f, 0.f};
  f32x4 acc[7];
#pragma unroll
  for (int t = 0; t < 7; ++t) acc[t] = zf;
  const u16* Bb = Bsrc + ((size_t)b * 784 + n0) * 512;
  const u16* Ar = W + (size_t)(mt * 64 + wave * 16 + lm) * 512;
  for (int ks = 0; ks < 16; ++ks) {
    __syncthreads();
    for (int u = tid; u < 448; u += 256) {
      int row = u >> 2, seg = u & 3;
      int4 v = *reinterpret_cast<const int4*>(Bb + (size_t)row * 512 + ks * 32 + seg * 8);
      *reinterpret_cast<int4*>(&Bl[row * 40 + seg * 8]) = v;
    }
    __syncthreads();
    bf16x8 af = ld_bf8(Ar + ks * 32 + lq * 8);
#pragma unroll
    for (int t = 0; t < 7; ++t) {
      bf16x8 bf8 = ld_bf8(&Bl[(t * 16 + lm) * 40 + lq * 8]);
      acc[t] = MFMA16(af, bf8, acc[t]);
    }
  }
  const int og = mt * 64 + wave * 16 + lq * 4;
  float sc[4], bi[4];
#pragma unroll
  for (int r = 0; r < 4; ++r) { sc[r] = gv[og + r] * INVS; bi[r] = bv[og + r]; }
#pragma unroll
  for (int t = 0; t < 7; ++t) {
    int j = n0 + t * 16 + lm;
    float4 o4;
    o4.x = acc[t][0] * sc[0] + bi[0];
    o4.y = acc[t][1] * sc[1] + bi[1];
    o4.z = acc[t][2] * sc[2] + bi[2];
    o4.w = acc[t][3] * sc[3] + bi[3];
    *reinterpret_cast<float4*>(outT + ((size_t)b * 784 + j) * 512 + og) = o4;
  }
}

// ---------------- fused attention per (b, g, 16-row i-tile) ----------------
// R4 LDS layout: Pl u16[16 + 16*872]; row m base = 16+m*872; cols [0,784) hold
// fp16 logits (phase 1-2), then bf16 P~ in-place (same addr, read-before-write,
// wave-lockstep-safe). Header [0,16) + right pads [784,872) are zero for
// guard-free Psh gather (negative reach lands in prev row's zero pad).
// Row stride 872 u16 = 436 words (mod 32 = 20) -> 2-way-max banks on b128.
__global__ __launch_bounds__(256) void k_attn(
    const u16* __restrict__ Qs, const u16* __restrict__ Ks, const u16* __restrict__ Vs,
    const u16* __restrict__ relq, const u16* __restrict__ relk, const u16* __restrict__ relv,
    const float* __restrict__ g_sim, const float* __restrict__ g_out,
    const float* __restrict__ b_out, float* __restrict__ binT) {
  const int b = blockIdx.z, g = blockIdx.y, i0 = blockIdx.x * 16;
  const int tid = threadIdx.x, lane = tid & 63, wave = tid >> 6;
  const int lm = lane & 15, lq = lane >> 4;
  __shared__ __align__(16) u16 Pl[16 + 16 * 872];
  __shared__ __align__(16) float KRs[4][16][34];  // per-wave KR band tile
  __shared__ float WM[4][16];                     // per-wave row max
  __shared__ float rstat[16];
  // zero header [0,16) and right pads [784,872) of each row
  for (int u = tid; u < 1424; u += 256) {
    int idx = (u < 16) ? u : (16 + ((u - 16) / 88) * 872 + 784 + (u - 16) % 88);
    Pl[idx] = 0;
  }
  const float s0 = g_sim[g] * INVS, s1 = g_sim[8 + g] * INVS, s2 = g_sim[16 + g] * INVS;
  const size_t bg = (size_t)b * 8 + g;
  const u16* Qb = Qs + bg * 784 * 32;
  const u16* Kb = Ks + bg * 784 * 32;
  const u16* Vb = Vs + bg * 64 * 784;
  const bf16x8 aq = ld_bf8(Qb + (i0 + lm) * 32 + lq * 8);
  const f32x4 zf = {0.f, 0.f, 0.f, 0.f};
  // ---- phase 1: logits -> fp16 LDS; wave owns j-tiles wave, wave+4, ... ----
  float vmax[4] = {-1e30f, -1e30f, -1e30f, -1e30f};
  bf16x8 kfc, bq0c, bq1c, bk0c, bk1c;
  {
    const int j0 = wave * 16;
    const int d0 = 768 + i0 - j0, e0 = 768 + j0 - i0;
    kfc = ld_bf8(Kb + (j0 + lm) * 32 + lq * 8);
    bq0c = ld_bf8(relq + (d0 + lm) * 32 + lq * 8);
    bq1c = ld_bf8(relq + (d0 + 16 + lm) * 32 + lq * 8);
    bk0c = ld_bf8(relk + (e0 + lm) * 32 + lq * 8);
    bk1c = ld_bf8(relk + (e0 + 16 + lm) * 32 + lq * 8);
  }
  int jt = wave;
  for (int rr = 0; rr < 13; ++rr) {
    const int jtn = jt + 4;
    bf16x8 kfn = kfc, bq0n = bq0c, bq1n = bq1c, bk0n = bk0c, bk1n = bk1c;
    if (jtn < 49) {
      const int j0n = jtn * 16;
      const int d0 = 768 + i0 - j0n, e0 = 768 + j0n - i0;
      kfn = ld_bf8(Kb + (j0n + lm) * 32 + lq * 8);
      bq0n = ld_bf8(relq + (d0 + lm) * 32 + lq * 8);
      bq1n = ld_bf8(relq + (d0 + 16 + lm) * 32 + lq * 8);
      bk0n = ld_bf8(relk + (e0 + lm) * 32 + lq * 8);
      bk1n = ld_bf8(relk + (e0 + 16 + lm) * 32 + lq * 8);
    }
    if (jt < 49) {
      const int j0 = jt * 16;
      f32x4 aqk = MFMA16(aq, kfc, zf);      // qk[i][j]
      f32x4 q0 = MFMA16(aq, bq0c, zf);      // QRt[i][d] cols 0..15
      f32x4 q1 = MFMA16(aq, bq1c, zf);      // cols 16..31
      f32x4 k0 = MFMA16(kfc, bk0c, zf);     // KRt[j][s] cols 0..15
      f32x4 k1 = MFMA16(kfc, bk1c, zf);
#pragma unroll
      for (int r = 0; r < 4; ++r) {
        int m = lq * 4 + r;
        KRs[wave][m][lm] = k0[r];
        KRs[wave][m][16 + lm] = k1[r];
      }
      // per-wave LDS RAW: compiler inserts lgkmcnt wait, no barrier needed
#pragma unroll
      for (int r = 0; r < 4; ++r) {
        int m = lq * 4 + r, n = lm;
        int c = m - n + 15;  // qr gather col
        int srcl = (c & 15) | (lane & 48);
        float t0 = bpermf(q0[r], srcl), t1 = bpermf(q1[r], srcl);
        float qv = (c & 16) ? t1 : t0;
        float kv = KRs[wave][n][n - m + 15];
        float val = aqk[r] * s0 + qv * s1 + kv * s2;  // b_sim drops (shift-invariant)
        vmax[r] = fmaxf(vmax[r], val);
        _Float16 hv = (_Float16)val;
        Pl[16 + m * 872 + j0 + n] = __builtin_bit_cast(u16, hv);
      }
    }
    jt = jtn;
    kfc = kfn; bq0c = bq0n; bq1c = bq1n; bk0c = bk0n; bk1c = bk1n;
  }
  // wave-local row max reduce over n (lm bits)
#pragma unroll
  for (int r = 0; r < 4; ++r) {
#pragma unroll
    for (int d = 1; d < 16; d <<= 1) vmax[r] = fmaxf(vmax[r], __shfl_xor(vmax[r], d, 64));
  }
  if (lm == 0) {
#pragma unroll
    for (int r = 0; r < 4; ++r) WM[wave][lq * 4 + r] = vmax[r];
  }
  __syncthreads();
  // ---- phase 2: softmax, fp16 -> bf16 P~ IN-PLACE (same index, same size) ----
  {
    const int row = tid >> 4, sub = tid & 15;
    u16* Pr = &Pl[16 + row * 872];
    float gmax = fmaxf(fmaxf(WM[0][row], WM[1][row]), fmaxf(WM[2][row], WM[3][row]));
    float sm = 0.f;
    for (int k = 0; k < 49; ++k) {
      int j = sub + 16 * k;
      _Float16 hv = __builtin_bit_cast(_Float16, Pr[j]);
      float e = __expf((float)hv - gmax);
      sm += e;
      Pr[j] = f2bf(e);
    }
#pragma unroll
    for (int d = 1; d < 16; d <<= 1) sm += __shfl_xor(sm, d, 64);
    if (sub == 0) rstat[row] = 1.0f / sm;
  }
  __syncthreads();
  // ---- phase 3: PV; wave = c-chunk of 16; sv = P~ @ V^T, sve = Psh @ relv^T ----
  f32x4 accV = zf, accE = zf;
  const int coff = wave * 16;
  const u16* Vr = Vb + (size_t)(coff + lm) * 784;
  const u16* Rr = relv + (size_t)(coff + lm) * 1600 + i0;
  const u16* Prow = &Pl[16 + lm * 872];
  for (int ks = 0; ks < 25; ++ks) {
    bf16x8 ap = ld_bf8(Prow + ks * 32 + lq * 8);  // cols>=784 read zero pad
    bf16x8 bv = ld_bf8(Vr + ks * 32 + lq * 8);
    accV = MFMA16(ap, bv, accV);
    const int base = 783 + lm - ks * 32 - lq * 8;  // Psh gather; pads/header give 0
    u16 h[8];
#pragma unroll
    for (int e = 0; e < 8; ++e) h[e] = Prow[base - e];
    bf16x8 ash = pack8(h);
    bf16x8 br = ld_bf8(Rr + ks * 32 + lq * 8);
    accE = MFMA16(ash, br, accE);
  }
  // ---- epilogue: binary[b, g*64+c, i] = bn(sv)+bn(sve), write (i, c) layout ----
  const int c = coff + lm;
  const int oi = g * 128 + 2 * c;
  const float so0 = g_out[oi] * INVS, bo0 = b_out[oi];
  const float so1 = g_out[oi + 1] * INVS, bo1 = b_out[oi + 1];
#pragma unroll
  for (int r = 0; r < 4; ++r) {
    int row = lq * 4 + r;
    float rl = rstat[row];
    float val = accV[r] * rl * so0 + bo0 + accE[r] * rl * so1 + bo1;
    binT[((size_t)b * 784 + i0 + row) * 512 + g * 64 + c] = val;
  }
}

// ---------------- rw GEMM: relu(concat(unary,binary)) -> relu(bn) -> rT bf16 ----------------
__global__ __launch_bounds__(256) void k_gemm_rw(
    const u16* __restrict__ W, const float* __restrict__ unT, const float* __restrict__ binT,
    const float* __restrict__ gv, const float* __restrict__ bv, u16* __restrict__ rT) {
  const int b = blockIdx.z, mt = blockIdx.y, n0 = blockIdx.x * 112;
  const int tid = threadIdx.x, lane = tid & 63, wave = tid >> 6;
  const int lm = lane & 15, lq = lane >> 4;
  __shared__ __align__(16) u16 Bl[112 * 40];
  f32x4 zf = {0.f, 0.f, 0.f, 0.f};
  f32x4 acc[7];
#pragma unroll
  for (int t = 0; t < 7; ++t) acc[t] = zf;
  const u16* Ar = W + (size_t)(mt * 64 + wave * 16 + lm) * 1024;
  for (int ks = 0; ks < 32; ++ks) {
    __syncthreads();
    const float* src_base = (ks < 16) ? unT : binT;
    const int k0 = (ks & 15) * 32;
    for (int u = tid; u < 448; u += 256) {
      int row = u >> 2, seg = u & 3;
      const float* sp = src_base + ((size_t)b * 784 + n0 + row) * 512 + k0 + seg * 8;
      float4 v0 = *reinterpret_cast<const float4*>(sp);
      float4 v1 = *reinterpret_cast<const float4*>(sp + 4);
      u16 h[8] = {f2bf(fmaxf(v0.x, 0.f)), f2bf(fmaxf(v0.y, 0.f)),
                  f2bf(fmaxf(v0.z, 0.f)), f2bf(fmaxf(v0.w, 0.f)),
                  f2bf(fmaxf(v1.x, 0.f)), f2bf(fmaxf(v1.y, 0.f)),
                  f2bf(fmaxf(v1.z, 0.f)), f2bf(fmaxf(v1.w, 0.f))};
      *reinterpret_cast<int4*>(&Bl[row * 40 + seg * 8]) = __builtin_bit_cast(int4, pack8(h));
    }
    __syncthreads();
    bf16x8 af = ld_bf8(Ar + ks * 32 + lq * 8);
#pragma unroll
    for (int t = 0; t < 7; ++t) {
      bf16x8 bf8 = ld_bf8(&Bl[(t * 16 + lm) * 40 + lq * 8]);
      acc[t] = MFMA16(af, bf8, acc[t]);
    }
  }
  const int og = mt * 64 + wave * 16 + lq * 4;
  float sc[4], bi[4];
#pragma unroll
  for (int r = 0; r < 4; ++r) { sc[r] = gv[og + r] * INVS; bi[r] = bv[og + r]; }
#pragma unroll
  for (int t = 0; t < 7; ++t) {
    int j = n0 + t * 16 + lm;
    u16 h[4];
#pragma unroll
    for (int r = 0; r < 4; ++r) h[r] = f2bf(fmaxf(acc[t][r] * sc[r] + bi[r], 0.f));
    u32 lo = (u32)h[0] | ((u32)h[1] << 16);
    u32 hi = (u32)h[2] | ((u32)h[3] << 16);
    *reinterpret_cast<int2*>(rT + ((size_t)b * 784 + j) * 512 + og) = make_int2((int)lo, (int)hi);
  }
}

// ---------------- pw GEMM + sigmoid gate + final fuse -> d_out ----------------
__global__ __launch_bounds__(256) void k_gemm_pw(
    const u16* __restrict__ W, const u16* __restrict__ rT,
    const float* __restrict__ gv, const float* __restrict__ bv,
    const float* __restrict__ binT, const float* __restrict__ unT,
    float* __restrict__ out) {
  const int b = blockIdx.z, mt = blockIdx.y, n0 = blockIdx.x * 112;
  const int tid = threadIdx.x, lane = tid & 63, wave = tid >> 6;
  const int lm = lane & 15, lq = lane >> 4;
  __shared__ __align__(16) u16 Bl[112 * 40];
  f32x4 zf = {0.f, 0.f, 0.f, 0.f};
  f32x4 acc[7];
#pragma unroll
  for (int t = 0; t < 7; ++t) acc[t] = zf;
  const u16* Bb = rT + ((size_t)b * 784 + n0) * 512;
  const u16* Ar = W + (size_t)(mt * 64 + wave * 16 + lm) * 512;
  for (int ks = 0; ks < 16; ++ks) {
    __syncthreads();
    for (int u = tid; u < 448; u += 256) {
      int row = u >> 2, seg = u & 3;
      int4 v = *reinterpret_cast<const int4*>(Bb + (size_t)row * 512 + ks * 32 + seg * 8);
      *reinterpret_cast<int4*>(&Bl[row * 40 + seg * 8]) = v;
    }
    __syncthreads();
    bf16x8 af = ld_bf8(Ar + ks * 32 + lq * 8);
#pragma unroll
    for (int t = 0; t < 7; ++t) {
      bf16x8 bf8 = ld_bf8(&Bl[(t * 16 + lm) * 40 + lq * 8]);
      acc[t] = MFMA16(af, bf8, acc[t]);
    }
  }
  const int og = mt * 64 + wave * 16 + lq * 4;
  float sc[4], bi[4];
#pragma unroll
  for (int r = 0; r < 4; ++r) { sc[r] = gv[og + r] * INVS; bi[r] = bv[og + r]; }
#pragma unroll
  for (int t = 0; t < 7; ++t) {
    int j = n0 + t * 16 + lm;
    float4 bin4 = *reinterpret_cast<const float4*>(binT + ((size_t)b * 784 + j) * 512 + og);
    float4 un4 = *reinterpret_cast<const float4*>(unT + ((size_t)b * 784 + j) * 512 + og);
    float binv[4] = {bin4.x, bin4.y, bin4.z, bin4.w};
    float unv[4] = {un4.x, un4.y, un4.z, un4.w};
#pragma unroll
    for (int r = 0; r < 4; ++r) {
      float gt = 1.f / (1.f + __expf(-(acc[t][r] * sc[r] + bi[r])));
      out[((size_t)b * 512 + og + r) * 784 + j] = gt * binv[r] + unv[r];
    }
  }
}

extern "C" void kernel_launch(void* const* d_in, const int* in_sizes, int n_in,
                              void* d_out, int out_size, void* d_ws, size_t ws_size,
                              hipStream_t stream) {
  const float* x = (const float*)d_in[0];
  const float* qkv_w = (const float*)d_in[1];
  const float* g_qkv = (const float*)d_in[2];
  const float* b_qkv = (const float*)d_in[3];
  const float* g_sim = (const float*)d_in[4];
  // d_in[5] = b_sim: unused (softmax is shift-invariant per (b,g) row)
  const float* g_out = (const float*)d_in[6];
  const float* b_out = (const float*)d_in[7];
  const float* relative = (const float*)d_in[8];
  const float* xw1 = (const float*)d_in[9];
  const float* xw2 = (const float*)d_in[10];
  const float* g_x = (const float*)d_in[11];
  const float* b_x = (const float*)d_in[12];
  const float* rw = (const float*)d_in[13];
  const float* g_r = (const float*)d_in[14];
  const float* b_r = (const float*)d_in[15];
  const float* pw = (const float*)d_in[16];
  const float* g_p = (const float*)d_in[17];
  const float* b_p = (const float*)d_in[18];

  char* p = (char*)d_ws;
  auto take = [&](size_t n) { char* q = p; p += (n + 255) & ~(size_t)255; return q; };
  u16* xT = (u16*)take((size_t)8 * 784 * 512 * 2);
  u16* Wq = (u16*)take((size_t)1024 * 512 * 2);
  u16* W2 = (u16*)take((size_t)512 * 512 * 2);
  u16* Wr = (u16*)take((size_t)512 * 1024 * 2);
  u16* Wp = (u16*)take((size_t)512 * 512 * 2);
  u16* W1t = (u16*)take((size_t)294912 * 2);
  u16* relq = (u16*)take((size_t)51200 * 2);
  u16* relk = (u16*)take((size_t)51200 * 2);
  u16* relv = (u16*)take((size_t)102400 * 2);
  u16* Qs = (u16*)take((size_t)8 * 8 * 784 * 32 * 2);
  u16* Ks = (u16*)take((size_t)8 * 8 * 784 * 32 * 2);
  u16* Vs = (u16*)take(((size_t)8 * 8 * 64 * 784 + 64) * 2);  // +64 pad for K=800 reads
  u16* umid = (u16*)take((size_t)8 * 784 * 512 * 2);
  float* unT = (float*)take((size_t)8 * 784 * 512 * 4);
  float* binT = (float*)take((size_t)8 * 784 * 512 * 4);
  u16* rT = (u16*)take((size_t)8 * 784 * 512 * 2);

  k_prep<<<dim3(8096), dim3(256), 0, stream>>>(qkv_w, xw2, rw, pw, xw1, relative,
                                               Wq, W2, Wr, Wp, W1t, relq, relk, relv);
  k_transpose<<<dim3(25, 8, 8), dim3(256), 0, stream>>>(x, xT);
  k_gemm_qkv<<<dim3(7, 16, 8), dim3(256), 0, stream>>>(Wq, xT, g_qkv, b_qkv, Qs, Ks, Vs);
  k_conv1<<<dim3(7, 8, 8), dim3(256), 0, stream>>>(xT, W1t, umid);
  k_gemm_x2<<<dim3(7, 8, 8), dim3(256), 0, stream>>>(W2, umid, g_x, b_x, unT);
  k_attn<<<dim3(49, 8, 8), dim3(256), 0, stream>>>(Qs, Ks, Vs, relq, relk, relv,
                                                   g_sim, g_out, b_out, binT);
  k_gemm_rw<<<dim3(7, 8, 8), dim3(256), 0, stream>>>(Wr, unT, binT, g_r, b_r, rT);
  k_gemm_pw<<<dim3(7, 8, 8), dim3(256), 0, stream>>>(Wp, rT, g_p, b_p, binT, unT,
                                                     (float*)d_out);
}